// Round 2
// 984.861 us; speedup vs baseline: 1.7051x; 1.7051x over previous
//
#include <hip/hip_runtime.h>
#include <hip/hip_bf16.h>

// ---------------------------------------------------------------------------
// Decoder_996432412985: attention LSTM decoder on MI355X.
// B=64, FMAP=512, ENC=256, DEC=512, ATTN=256, NC+2=98, T+1=31, H=8, W=32.
// R11 (= R10 with workspace-safety fixes):
// logits/masks/glimpses do NOT feed the recurrence (teacher forcing).
// Sequential phase = LSTM cells ONLY (32 light launches, 64 blocks each,
// h1 history stored to h1_all). Attention batched over all 1984=64x31 rows:
//   k_eh      : EH = H1 @ e_lstm_w^T            (MFMA GEMM 1984x256x512)
//   k_score   : tanh(EH+ef)@a_w -> softmax -> masks (512 blocks)
//   k_glimpse : per-b Fmap(512x256) @ MaskT(256x31)  (MFMA, fp32 fmap read
//               once, converted in-reg -> no 16MB fmapb buffer)
//   k_logits  : [h1 | glimpse](1984x1024) @ fc_w^T   (MFMA GEMM)
// EHf/maskb/glb alias padT's region (padT dead after k_conv) -> total carve
// ~45 MB, within a few % of the known-good R9 footprint.
// ---------------------------------------------------------------------------

typedef __bf16 bf16_8 __attribute__((ext_vector_type(8)));
typedef __bf16 bf16_4 __attribute__((ext_vector_type(4)));
typedef __bf16 bf16_2 __attribute__((ext_vector_type(2)));
typedef float f32x4 __attribute__((ext_vector_type(4)));

typedef __hip_bfloat16 bf;

__device__ __forceinline__ float b2f(bf h) { return __bfloat162float(h); }
__device__ __forceinline__ bf f2b(float f) { return __float2bfloat16(f); }
__device__ __forceinline__ float sigm(float x) { return 1.0f / (1.0f + __expf(-x)); }
__device__ __forceinline__ float tanh_f(float x) { return 1.0f - 2.0f / (1.0f + __expf(2.0f * x)); }
__device__ __forceinline__ f32x4 mfma16(bf16_8 a, bf16_8 b, f32x4 c) {
    return __builtin_amdgcn_mfma_f32_16x16x32_bf16(a, b, c, 0, 0, 0);
}

#define NB 64
#define FMAP 512
#define ENC 256
#define DEC 512
#define ATTN 256
#define NC2 98
#define TT 31
#define HW 256
#define PW 34
#define PPOS 340  // 10*34 padded spatial
#define NROWS 1984  // 31*64 (t-major rows)

// ------------------------- dtype normalization -----------------------------

__global__ void k_detect(const int* __restrict__ t32, int* __restrict__ flags) {
    __shared__ int i64f;
    int tid = threadIdx.x;
    if (tid == 0) i64f = 1;
    __syncthreads();
    for (int i = tid; i < 960; i += 256)
        if (t32[2 * i + 1] != 0) i64f = 0;
    __syncthreads();
    if (tid == 0) { flags[0] = 0; flags[1] = i64f; }
}

#define N_CVT 17
struct CvtTab {
    const void* src[N_CVT];
    unsigned long long off[N_CVT];
    int n[N_CVT];
};

__global__ void k_cvt(CvtTab tab, unsigned char* __restrict__ ws) {
    int id = blockIdx.y;
    int n = tab.n[id];
    bf* dst = (bf*)(ws + tab.off[id]);
    const float* sf = (const float*)tab.src[id];
    for (int i = blockIdx.x * 256 + threadIdx.x; i < n; i += 256 * gridDim.x)
        dst[i] = f2b(sf[i]);
}

// ------------------------- prep kernels ------------------------------------

// initial h/c: h0 parity 1 (first lstm0 at s=0 reads pprev=1); h1(-1) -> slot 0
__global__ void k_init_state(const float* __restrict__ h0, const float* __restrict__ c0,
                             bf* __restrict__ h0b, bf* __restrict__ h1_all,
                             float* __restrict__ c0f, float* __restrict__ c1f) {
    int i = blockIdx.x * 256 + threadIdx.x;
    if (i >= NB * DEC) return;
    h0b[32768 + i] = f2b(h0[i]);
    h1_all[i] = f2b(h0[NB * DEC + i]);
    c0f[i] = c0[i];
    c1f[i] = c0[NB * DEC + i];
}

__global__ void k_embed(const int* __restrict__ target, const bf* __restrict__ emb,
                        bf* __restrict__ x_seq, const int* __restrict__ flags) {
    int t = blockIdx.x, b = blockIdx.y, e = threadIdx.x;
    int lab = 0;
    if (t > 0) {
        int idx = b * 30 + (t - 1);
        lab = flags[1] ? target[2 * idx] : target[idx];
    }
    lab = min(max(lab, 0), 96);
    x_seq[(t * NB + b) * ENC + e] = emb[lab * ENC + e];
}

__global__ void k_wt(const bf* __restrict__ ew, bf* __restrict__ wt) {
    int dydx = blockIdx.x, a = blockIdx.y;
    for (int c = threadIdx.x; c < FMAP; c += 256)
        wt[(dydx * ATTN + a) * FMAP + c] = ew[(a * FMAP + c) * 9 + dydx];
}

// zero all of padT (halo rows stay zero; interior overwritten by k_padT)
__global__ void k_zero(unsigned long long* __restrict__ p) {
    p[blockIdx.x * 256 + threadIdx.x] = 0ULL;
}

// padT[b][(y+1)*34+(x+1)][c] = bf16(fmap_f32[b][c][y*32+x]); LDS tile transpose
__global__ __launch_bounds__(256) void k_padT(const float* __restrict__ fmapf,
                                              bf* __restrict__ padT) {
    __shared__ bf T3[64 * 258];
    int b = blockIdx.x, cq = blockIdx.y;  // grid (64, 8)
    int tid = threadIdx.x;
    for (int c_l = 0; c_l < 64; c_l++) {
        float v = fmapf[((size_t)(b * FMAP + cq * 64 + c_l)) * HW + tid];
        T3[c_l * 258 + tid] = f2b(v);
    }
    __syncthreads();
    int c_o = tid & 63, pg = tid >> 6;
    for (int it = 0; it < 64; it++) {
        int pos = it * 4 + pg, y = pos >> 5, x = pos & 31;
        padT[((size_t)b * PPOS + (y + 1) * PW + (x + 1)) * FMAP + cq * 64 + c_o] =
            T3[c_o * 258 + pos];
    }
}

// conv3x3 as MFMA GEMM: LDS tile staged from padT (straight copy, coalesced).
__global__ __launch_bounds__(256) void k_conv(const bf* __restrict__ padT,
                                              const bf* __restrict__ wt,
                                              const bf* __restrict__ efb,
                                              bf* __restrict__ ef) {
    __shared__ __align__(16) bf T[257 * 72];
    int b = blockIdx.x, aHalf = blockIdx.y, pHalf = blockIdx.z;
    int tid = threadIdx.x, wv = tid >> 6, lane = tid & 63;
    int q = lane >> 4, l = lane & 15;
    int abase = aHalf * 128 + wv * 32;

    for (int i = tid; i < 72; i += 256) T[256 * 72 + i] = f2b(0.0f);  // halo row

    const bf* pb = padT + (size_t)b * PPOS * FMAP;
    f32x4 acc[2][8] = {};
    for (int cQ = 0; cQ < 8; cQ++) {
        __syncthreads();
#pragma unroll
        for (int j = 0; j < 8; j++) {
            int chunk = j * 256 + tid;       // 2048 chunks of 8 bf16
            int row = chunk >> 3, g = chunk & 7;
            int ppos = 35 + (row >> 5) * PW + (row & 31);
            *(bf16_8*)(T + row * 72 + g * 8) =
                *(const bf16_8*)(pb + (size_t)ppos * FMAP + cQ * 64 + g * 8);
        }
        __syncthreads();
        for (int dydx = 0; dydx < 9; dydx++) {
            int dy = dydx / 3, dx = dydx % 3;
            int rowv[8];
#pragma unroll
            for (int nt = 0; nt < 8; nt++) {
                int y = pHalf * 4 + (nt >> 1);
                int yp = y + dy - 1;
                int x = (nt & 1) * 16 + l;
                int xp = x + dx - 1;
                bool ok = (yp >= 0 && yp < 8 && xp >= 0 && xp < 32);
                rowv[nt] = ok ? (yp * 32 + xp) : 256;
            }
            const bf* wtd = wt + ((size_t)dydx * ATTN) * FMAP;
#pragma unroll
            for (int ck = 0; ck < 2; ck++) {
                int kg = cQ * 64 + ck * 32 + q * 8;
                bf16_8 afr[2];
#pragma unroll
                for (int mt = 0; mt < 2; mt++)
                    afr[mt] = *(const bf16_8*)(wtd + (abase + mt * 16 + l) * FMAP + kg);
#pragma unroll
                for (int nt = 0; nt < 8; nt++) {
                    bf16_8 bfr = *(const bf16_8*)(T + rowv[nt] * 72 + ck * 32 + q * 8);
                    acc[0][nt] = mfma16(afr[0], bfr, acc[0][nt]);
                    acc[1][nt] = mfma16(afr[1], bfr, acc[1][nt]);
                }
            }
        }
    }
#pragma unroll
    for (int mt = 0; mt < 2; mt++)
#pragma unroll
        for (int nt = 0; nt < 8; nt++) {
            int a0 = abase + mt * 16 + q * 4;
            int pos = pHalf * 128 + nt * 16 + l;
            bf16_4 o;
#pragma unroll
            for (int r = 0; r < 4; r++) o[r] = f2b(acc[mt][nt][r] + b2f(efb[a0 + r]));
            *(bf16_4*)(ef + ((size_t)(b * HW + pos)) * ATTN + a0) = o;
        }
}

// ---------------- sequential phase: LSTM cells only -------------------------
// Launch s (0..31): blocks 32..63 -> lstm0(s) [s<=30]; blocks 0..31 ->
// lstm1(s-1) [s>=1]. h0 ping-pong (parity s&1); h1 history: h1(t) at
// h1_all slot t+1 (slot 0 = initial h1).

__global__ __launch_bounds__(256) void k_lstm(
        int s,
        const bf* __restrict__ x_seq,
        const bf* __restrict__ Wih0, const bf* __restrict__ Whh0,
        const bf* __restrict__ bih0, const bf* __restrict__ bhh0,
        const bf* __restrict__ Wih1, const bf* __restrict__ Whh1,
        const bf* __restrict__ bih1, const bf* __restrict__ bhh1,
        bf* __restrict__ h0b, bf* __restrict__ h1_all,
        float* __restrict__ c0f, float* __restrict__ c1f) {
    const int blk = blockIdx.x, tid = threadIdx.x;
    const int wv = tid >> 6, lane = tid & 63;
    const int q = lane >> 4, l = lane & 15;
    const int pcur = s & 1, pprev = (s + 1) & 1;

    if (blk >= 32) {
        // ---------------- lstm0(s) ----------------
        if (s > 30) return;
        int d0 = (blk - 32) * 16;
        const bf* xt = x_seq + (size_t)s * NB * ENC;
        const bf* hprev = h0b + pprev * 32768;
        bf* hnew = h0b + pcur * 32768;
        f32x4 acc[4] = {};
        for (int k0 = 0; k0 < ENC; k0 += 32) {
            bf16_8 af = *(const bf16_8*)(xt + (wv * 16 + l) * ENC + k0 + q * 8);
#pragma unroll
            for (int g = 0; g < 4; g++) {
                bf16_8 bfr = *(const bf16_8*)(Wih0 + (g * 512 + d0 + l) * ENC + k0 + q * 8);
                acc[g] = mfma16(af, bfr, acc[g]);
            }
        }
        for (int k0 = 0; k0 < DEC; k0 += 32) {
            bf16_8 af = *(const bf16_8*)(hprev + (wv * 16 + l) * DEC + k0 + q * 8);
#pragma unroll
            for (int g = 0; g < 4; g++) {
                bf16_8 bfr = *(const bf16_8*)(Whh0 + (g * 512 + d0 + l) * DEC + k0 + q * 8);
                acc[g] = mfma16(af, bfr, acc[g]);
            }
        }
        int d = d0 + l;
        float bi[4];
#pragma unroll
        for (int g = 0; g < 4; g++)
            bi[g] = b2f(bih0[g * 512 + d]) + b2f(bhh0[g * 512 + d]);
#pragma unroll
        for (int r = 0; r < 4; r++) {
            int bb = wv * 16 + q * 4 + r;
            float gi = sigm(acc[0][r] + bi[0]);
            float gf = sigm(acc[1][r] + bi[1]);
            float gg = tanh_f(acc[2][r] + bi[2]);
            float go = sigm(acc[3][r] + bi[3]);
            float c = gf * c0f[bb * DEC + d] + gi * gg;
            c0f[bb * DEC + d] = c;
            hnew[bb * DEC + d] = f2b(go * tanh_f(c));
        }
    } else {
        // ---------------- lstm1(s-1) ----------------
        if (s < 1) return;
        int d0 = blk * 16;
        const bf* h0n = h0b + pprev * 32768;                 // h0 state(s-1)
        const bf* h1p = h1_all + (size_t)(s - 1) * 32768;    // h1 state(s-2)
        bf* h1n = h1_all + (size_t)s * 32768;                // h1 state(s-1)
        f32x4 acc[4] = {};
        for (int ph = 0; ph < 2; ph++) {
            const bf* Ain = ph ? h1p : h0n;
            const bf* Wp = ph ? Whh1 : Wih1;
            for (int k0 = 0; k0 < DEC; k0 += 32) {
                bf16_8 af = *(const bf16_8*)(Ain + (wv * 16 + l) * DEC + k0 + q * 8);
#pragma unroll
                for (int g = 0; g < 4; g++) {
                    bf16_8 bfr = *(const bf16_8*)(Wp + (g * 512 + d0 + l) * DEC + k0 + q * 8);
                    acc[g] = mfma16(af, bfr, acc[g]);
                }
            }
        }
        int d = d0 + l;
        float bi[4];
#pragma unroll
        for (int g = 0; g < 4; g++)
            bi[g] = b2f(bih1[g * 512 + d]) + b2f(bhh1[g * 512 + d]);
#pragma unroll
        for (int r = 0; r < 4; r++) {
            int bb = wv * 16 + q * 4 + r;
            float gi = sigm(acc[0][r] + bi[0]);
            float gf = sigm(acc[1][r] + bi[1]);
            float gg = tanh_f(acc[2][r] + bi[2]);
            float go = sigm(acc[3][r] + bi[3]);
            float c = gf * c1f[bb * DEC + d] + gi * gg;
            c1f[bb * DEC + d] = c;
            h1n[bb * DEC + d] = f2b(go * tanh_f(c));
        }
    }
}

// ---------------- batched attention phase ----------------------------------
// H1 rows: r = t*64+b -> (h1_all + 32768)[r*512 + k]  (slot t+1, row b).

// EH[r][a] = H1[r] . e_lstm_w[a] + b  (M=1984, N=256, K=512)
__global__ __launch_bounds__(256) void k_eh(const bf* __restrict__ h1_all,
                                            const bf* __restrict__ ew,
                                            const bf* __restrict__ eb,
                                            float* __restrict__ EHf) {
    int mtile = blockIdx.x, ntile = blockIdx.y;  // grid (31, 4)
    int tid = threadIdx.x, wv = tid >> 6, lane = tid & 63;
    int q = lane >> 4, l = lane & 15;
    const bf* A = h1_all + 32768;
    f32x4 acc[4] = {};
    for (int k0 = 0; k0 < DEC; k0 += 32) {
        bf16_8 af = *(const bf16_8*)(A + (size_t)(mtile * 64 + wv * 16 + l) * DEC + k0 + q * 8);
#pragma unroll
        for (int g = 0; g < 4; g++) {
            bf16_8 bfr = *(const bf16_8*)(ew + (size_t)(ntile * 64 + g * 16 + l) * DEC + k0 + q * 8);
            acc[g] = mfma16(af, bfr, acc[g]);
        }
    }
#pragma unroll
    for (int g = 0; g < 4; g++) {
        int col = ntile * 64 + g * 16 + l;
        float bias = b2f(eb[col]);
#pragma unroll
        for (int r = 0; r < 4; r++) {
            int m = mtile * 64 + wv * 16 + q * 4 + r;
            EHf[(size_t)m * ATTN + col] = acc[g][r] + bias;
        }
    }
}

// score + softmax + masks. grid (64 b, 8 tg); thread = pos; 4 t per block.
__global__ __launch_bounds__(256) void k_score(const float* __restrict__ EHf,
                                               const bf* __restrict__ ef,
                                               const bf* __restrict__ a_w,
                                               float* __restrict__ out_masks,
                                               bf* __restrict__ maskb) {
    __shared__ float ehs[4][ATTN];
    __shared__ float aws[ATTN];
    __shared__ float red[256];
    int b = blockIdx.x, tg = blockIdx.y, tid = threadIdx.x;

    aws[tid] = b2f(a_w[tid]);
#pragma unroll
    for (int j = 0; j < 4; j++) {
        int t = tg * 4 + j;
        ehs[j][tid] = (t <= 30) ? EHf[(size_t)(t * NB + b) * ATTN + tid] : 0.0f;
    }
    __syncthreads();

    const bf16_8* er = (const bf16_8*)(ef + ((size_t)b * HW + tid) * ATTN);
    float sj[4] = {0.f, 0.f, 0.f, 0.f};
#pragma unroll 4
    for (int a8 = 0; a8 < ATTN / 8; a8++) {
        bf16_8 e8 = er[a8];
#pragma unroll
        for (int jj = 0; jj < 8; jj++) {
            int a = a8 * 8 + jj;
            float efv = (float)e8[jj];
            float aw = aws[a];
            sj[0] += aw * tanh_f(ehs[0][a] + efv);
            sj[1] += aw * tanh_f(ehs[1][a] + efv);
            sj[2] += aw * tanh_f(ehs[2][a] + efv);
            sj[3] += aw * tanh_f(ehs[3][a] + efv);
        }
    }

#pragma unroll
    for (int j = 0; j < 4; j++) {
        int t = tg * 4 + j;
        red[tid] = sj[j];
        __syncthreads();
        for (int off = 128; off > 0; off >>= 1) {
            if (tid < off) red[tid] = fmaxf(red[tid], red[tid + off]);
            __syncthreads();
        }
        float mx = red[0];
        __syncthreads();
        float ex = __expf(sj[j] - mx);
        red[tid] = ex;
        __syncthreads();
        for (int off = 128; off > 0; off >>= 1) {
            if (tid < off) red[tid] += red[tid + off];
            __syncthreads();
        }
        float mk = ex / red[0];
        __syncthreads();
        if (t <= 30) {
            out_masks[((size_t)b * TT + t) * HW + tid] = mk;
            maskb[((size_t)b * 32 + t) * HW + tid] = f2b(mk);
        } else {
            maskb[((size_t)b * 32 + t) * HW + tid] = f2b(0.0f);
        }
    }
}

// glimpse: per-b GEMM C[c][t] = fmap[b](512x256) . maskb[b]^T(256x32).
// grid (64 b, 8 ctile). fp32 fmap loaded once, converted in-reg to bf16.
// Writes fp32 out + bf16 glb rows r = t*64+b.
__global__ __launch_bounds__(256) void k_glimpse(const float* __restrict__ fmapf,
                                                 const bf* __restrict__ maskb,
                                                 float* __restrict__ out_glimpses,
                                                 bf* __restrict__ glb) {
    int b = blockIdx.x, ctile = blockIdx.y;
    int tid = threadIdx.x, wv = tid >> 6, lane = tid & 63;
    int q = lane >> 4, l = lane & 15;
    const float* A = fmapf + (size_t)b * FMAP * HW + (size_t)(ctile * 64 + wv * 16 + l) * HW;
    const bf* B = maskb + (size_t)b * 32 * HW;
    f32x4 acc[2] = {};
    for (int k0 = 0; k0 < HW; k0 += 32) {
        const float* ap = A + k0 + q * 8;
        f32x4 v0 = *(const f32x4*)(ap);
        f32x4 v1 = *(const f32x4*)(ap + 4);
        bf16_8 af;
#pragma unroll
        for (int j = 0; j < 4; j++) { af[j] = (__bf16)v0[j]; af[4 + j] = (__bf16)v1[j]; }
#pragma unroll
        for (int tt = 0; tt < 2; tt++) {
            bf16_8 bfr = *(const bf16_8*)(B + (size_t)(tt * 16 + l) * HW + k0 + q * 8);
            acc[tt] = mfma16(af, bfr, acc[tt]);
        }
    }
#pragma unroll
    for (int tt = 0; tt < 2; tt++) {
        int t = tt * 16 + l;
        if (t > 30) continue;
#pragma unroll
        for (int r = 0; r < 4; r++) {
            int c = ctile * 64 + wv * 16 + q * 4 + r;
            float g = acc[tt][r];
            out_glimpses[((size_t)b * TT + t) * FMAP + c] = g;
            glb[(size_t)(t * NB + b) * FMAP + c] = f2b(g);
        }
    }
}

// logits: C[r][cls] = [H1 | glimpse][r] . fc_w[cls] + fc_b. M=1984,N=98,K=1024.
__global__ __launch_bounds__(256) void k_logits(const bf* __restrict__ h1_all,
                                                const bf* __restrict__ glb,
                                                const bf* __restrict__ fc_w,
                                                const bf* __restrict__ fc_b,
                                                float* __restrict__ out_logits) {
    int mtile = blockIdx.x, ntile = blockIdx.y;  // grid (31, 7)
    int tid = threadIdx.x, wv = tid >> 6, lane = tid & 63;
    int q = lane >> 4, l = lane & 15;
    const bf* A1 = h1_all + 32768;
    int cls = ntile * 16 + l;
    int clsc = min(cls, NC2 - 1);
    int rowA = mtile * 64 + wv * 16 + l;
    f32x4 acc = {};
    for (int k0 = 0; k0 < 1024; k0 += 32) {
        bf16_8 af;
        if (k0 < DEC)
            af = *(const bf16_8*)(A1 + (size_t)rowA * DEC + k0 + q * 8);
        else
            af = *(const bf16_8*)(glb + (size_t)rowA * FMAP + (k0 - DEC) + q * 8);
        bf16_8 bfr = *(const bf16_8*)(fc_w + (size_t)clsc * (DEC + FMAP) + k0 + q * 8);
        acc = mfma16(af, bfr, acc);
    }
    if (cls < NC2) {
        float bias = b2f(fc_b[cls]);
#pragma unroll
        for (int r = 0; r < 4; r++) {
            int m = mtile * 64 + wv * 16 + q * 4 + r;
            int bb = m & 63, t = m >> 6;
            out_logits[((size_t)bb * TT + t) * NC2 + cls] = acc[r] + bias;
        }
    }
}

// ------------------------------ host ---------------------------------------

extern "C" void kernel_launch(void* const* d_in, const int* in_sizes, int n_in,
                              void* d_out, int out_size, void* d_ws, size_t ws_size,
                              hipStream_t stream) {
    float* out = (float*)d_out;
    float* out_logits   = out;
    float* out_masks    = out + 64 * 31 * 98;
    float* out_glimpses = out + 64 * 31 * (98 + 256);

    unsigned char* ws = (unsigned char*)d_ws;
    unsigned long long off = 0;
    auto carve = [&](size_t bytes) {
        unsigned long long o = off;
        off = (off + bytes + 15ULL) & ~15ULL;
        return o;
    };

    unsigned long long o_flags = carve(64);
    static const int cvt_in[N_CVT] = {5, 6, 7, 8, 9, 10, 11, 12, 13, 14, 15, 16, 17, 18, 19, 20, 21};
    static const int cvt_n[N_CVT] = {
        97 * 256, 2048 * 256, 2048 * 512, 2048, 2048,
        2048 * 512, 2048 * 512, 2048, 2048,
        256 * 512, 256, 256 * 512 * 9, 256, 256, 1,
        98 * 1024, 98
    };
    CvtTab tab;
    for (int i = 0; i < N_CVT; i++) {
        tab.src[i] = d_in[cvt_in[i]];
        tab.n[i] = cvt_n[i];
        tab.off[i] = carve((size_t)cvt_n[i] * 2);
    }
    const bf* emb_c    = (const bf*)(ws + tab.off[0]);
    const bf* Wih0_c   = (const bf*)(ws + tab.off[1]);
    const bf* Whh0_c   = (const bf*)(ws + tab.off[2]);
    const bf* bih0_c   = (const bf*)(ws + tab.off[3]);
    const bf* bhh0_c   = (const bf*)(ws + tab.off[4]);
    const bf* Wih1_c   = (const bf*)(ws + tab.off[5]);
    const bf* Whh1_c   = (const bf*)(ws + tab.off[6]);
    const bf* bih1_c   = (const bf*)(ws + tab.off[7]);
    const bf* bhh1_c   = (const bf*)(ws + tab.off[8]);
    const bf* e_lstm_w_c = (const bf*)(ws + tab.off[9]);
    const bf* e_lstm_b_c = (const bf*)(ws + tab.off[10]);
    const bf* e_fmap_w_c = (const bf*)(ws + tab.off[11]);
    const bf* e_fmap_b_c = (const bf*)(ws + tab.off[12]);
    const bf* a_w_c    = (const bf*)(ws + tab.off[13]);
    const bf* fc_w_c   = (const bf*)(ws + tab.off[15]);
    const bf* fc_b_c   = (const bf*)(ws + tab.off[16]);

    bf*    wt     = (bf*)(ws + carve((size_t)9 * 256 * 512 * 2));
    bf*    ef     = (bf*)(ws + carve((size_t)64 * 256 * 256 * 2));
    bf*    x_seq  = (bf*)(ws + carve((size_t)31 * 64 * 256 * 2));
    bf*    h0b    = (bf*)(ws + carve(2 * 65536));
    bf*    h1_all = (bf*)(ws + carve((size_t)32 * 65536));   // 32 slots: h1(t) at t+1
    float* c0f    = (float*)(ws + carve(131072));
    float* c1f    = (float*)(ws + carve(131072));
    unsigned long long o_padT = carve((size_t)NB * PPOS * FMAP * 2);  // 22.28 MB
    bf*    padT   = (bf*)(ws + o_padT);
    int*   flags  = (int*)(ws + o_flags);

    // padT is dead after k_conv; reuse its region for the batched-attn
    // intermediates (5.1 MB < 22.28 MB).
    float* EHf    = (float*)(ws + o_padT);                               // 1984*256*4 = 2031616
    bf*    maskb  = (bf*)(ws + o_padT + 2031616ULL);                     // 64*32*256*2 = 1048576
    bf*    glb    = (bf*)(ws + o_padT + 2031616ULL + 1048576ULL);        // 1984*512*2 = 2031616

    k_detect<<<1, 256, 0, stream>>>((const int*)d_in[3], flags);
    k_cvt<<<dim3(256, N_CVT), 256, 0, stream>>>(tab, ws);
    k_init_state<<<128, 256, 0, stream>>>((const float*)d_in[1], (const float*)d_in[2],
                                          h0b, h1_all, c0f, c1f);
    k_embed<<<dim3(TT, NB), 256, 0, stream>>>((const int*)d_in[3], emb_c, x_seq, flags);
    k_wt<<<dim3(9, ATTN), 256, 0, stream>>>(e_fmap_w_c, wt);
    k_zero<<<10880, 256, 0, stream>>>((unsigned long long*)padT);
    k_padT<<<dim3(NB, 8), 256, 0, stream>>>((const float*)d_in[0], padT);
    k_conv<<<dim3(NB, 2, 2), 256, 0, stream>>>(padT, wt, e_fmap_b_c, ef);

    for (int s = 0; s <= 31; s++)
        k_lstm<<<64, 256, 0, stream>>>(s, x_seq, Wih0_c, Whh0_c, bih0_c, bhh0_c,
                                       Wih1_c, Whh1_c, bih1_c, bhh1_c,
                                       h0b, h1_all, c0f, c1f);

    k_eh<<<dim3(31, 4), 256, 0, stream>>>(h1_all, e_lstm_w_c, e_lstm_b_c, EHf);
    k_score<<<dim3(NB, 8), 256, 0, stream>>>(EHf, ef, a_w_c, out_masks, maskb);
    k_glimpse<<<dim3(NB, 8), 256, 0, stream>>>((const float*)d_in[0], maskb,
                                               out_glimpses, glb);
    k_logits<<<dim3(31, 7), 256, 0, stream>>>(h1_all, glb, fc_w_c, fc_b_c, out_logits);
}